// Round 9
// baseline (213.132 us; speedup 1.0000x reference)
//
#include <hip/hip_runtime.h>

#define NP 250000   // P: permutations
#define NN 100000   // N: nodes
#define NE 400000   // E: edges
#define LL 16
#define DD 16
#define MM (NP * LL)        // 4,000,000
#define NTILES (NP / 16)    // 15625 exact

typedef __bf16 bf16x8 __attribute__((ext_vector_type(8)));
typedef float f32x4 __attribute__((ext_vector_type(4)));

__device__ __forceinline__ float4 fma4(float a, float4 b, float4 c) {
    float4 r;
    r.x = fmaf(a, b.x, c.x);
    r.y = fmaf(a, b.y, c.y);
    r.z = fmaf(a, b.z, c.z);
    r.w = fmaf(a, b.w, c.w);
    return r;
}

// K-mapping for mfma_16x16x32_bf16, kb (0..7), lane (quad=lane>>4, c=lane&15):
//   d = 8*(quad&1) + j,  l = 8*(quad>>1) + kb
// wfrag[kb*512 + lane*8 + j] = weights[d][c][l]  (B-fragment order)
// Also: nfeat->bf16 table, bond->bf16, zero out, and be2: 2-bit packed
// bond indices  be2[m>>2] bits (2*(m&3)) = efeat_idx[e_col[m]].
// NOTE: total ws footprint is 4,208,320 B — empirically proven safe (R5-R7).
// Do NOT grow it: growing to 4.31 MB caused silent OOB corruption of
// harness state (R8 post-timing divergence).
__global__ __launch_bounds__(256) void init_kernel(
    const float* __restrict__ w,          // [16,16,16] (d,c,l)
    const float* __restrict__ nfeat,      // [N,16]
    const float* __restrict__ bond_emb,   // [4,16]
    const int* __restrict__ e_col,        // [M]
    const int* __restrict__ efeat_idx,    // [E]
    __bf16* __restrict__ wfrag,           // [8*64*8]
    __bf16* __restrict__ nfeat_bf,        // [N,16]
    __bf16* __restrict__ bond_bf,         // [4,16]
    unsigned char* __restrict__ be2,      // [M/4]
    float* __restrict__ out)              // [N,16] -> zeroed
{
    int t = blockIdx.x * 256 + threadIdx.x;
    if (t < 4096) {
        int kb = t >> 9;
        int lane = (t >> 3) & 63;
        int j = t & 7;
        int quad = lane >> 4, c = lane & 15;
        int d = ((quad & 1) << 3) + j;
        int l = ((quad >> 1) << 3) + kb;
        wfrag[t] = (__bf16)w[d * 256 + c * 16 + l];
    }
    if (t < NN * DD) {
        nfeat_bf[t] = (__bf16)nfeat[t];
        out[t] = 0.f;
    }
    if (t < 64) bond_bf[t] = (__bf16)bond_emb[t];
    if (t < MM / 4) {
        int4 ec = *(const int4*)(e_col + t * 4);
        unsigned int b0 = (unsigned int)efeat_idx[ec.x] & 3u;
        unsigned int b1 = (unsigned int)efeat_idx[ec.y] & 3u;
        unsigned int b2 = (unsigned int)efeat_idx[ec.z] & 3u;
        unsigned int b3 = (unsigned int)efeat_idx[ec.w] & 3u;
        be2[t] = (unsigned char)(b0 | (b1 << 2) | (b2 << 4) | (b3 << 6));
    }
}

// ONE 64-thread block (= one wave) per 16-perm tile.
// A[m=col][k=quad*8+j]; lane's rows are the 8 CONSECUTIVE
// l = 8*(quad>>1)..+7 of perm pbase+col.
// C/D: col=lane&15 (channel), row=quad*4+reg (perm-in-tile).
__global__ __launch_bounds__(64) void perm_kernel(
    const __bf16* __restrict__ nfeat_bf,   // [N,16] bf16
    const int* __restrict__ n_col,         // [M]
    const float* __restrict__ n_val,       // [M]
    const float* __restrict__ e_val,       // [M]
    const unsigned char* __restrict__ be2, // [M/4] packed bond indices
    const int* __restrict__ p_row,         // [P]
    const float* __restrict__ p_val,       // [P]
    const __bf16* __restrict__ wfrag,      // [8*64*8]
    const float* __restrict__ bias,        // [16]
    const __bf16* __restrict__ bond_bf,    // [4,16] bf16
    float* __restrict__ out)               // [N,16] zero-initialized
{
    const int lane = threadIdx.x;          // 0..63
    const int tile = blockIdx.x;
    const int quad = lane >> 4;
    const int col = lane & 15;
    const int half = quad & 1;    // d-half this lane holds
    const int lhalf = quad >> 1;  // l-half this lane covers

    const int pbase = tile * 16;
    const int mbase = (pbase + col) * LL + lhalf * 8;

    // issue ALL independent loads up front
    int4   nca = *(const int4*)(n_col + mbase);
    int4   ncb = *(const int4*)(n_col + mbase + 4);
    float4 nva = *(const float4*)(n_val + mbase);
    float4 nvb = *(const float4*)(n_val + mbase + 4);
    float4 eva = *(const float4*)(e_val + mbase);
    float4 evb = *(const float4*)(e_val + mbase + 4);
    unsigned int be16 = *(const unsigned short*)(be2 + (mbase >> 2));
    int4   pr  = *(const int4*)(p_row + pbase + quad * 4);
    float4 pvv = *(const float4*)(p_val + pbase + quad * 4);

    // weight B-fragments + bond rows + bias (L1/L2-hot, shared by all tiles)
    bf16x8 wf[8];
#pragma unroll
    for (int kb = 0; kb < 8; ++kb)
        wf[kb] = *(const bf16x8*)(wfrag + (kb * 64 + lane) * 8);
    const bf16x8 bq0 = *(const bf16x8*)(bond_bf + 0 * 16 + half * 8);
    const bf16x8 bq1 = *(const bf16x8*)(bond_bf + 1 * 16 + half * 8);
    const bf16x8 bq2 = *(const bf16x8*)(bond_bf + 2 * 16 + half * 8);
    const bf16x8 bq3 = *(const bf16x8*)(bond_bf + 3 * 16 + half * 8);
    const float bias_c = bias[col];

    int   ncs[8] = {nca.x, nca.y, nca.z, nca.w, ncb.x, ncb.y, ncb.z, ncb.w};
    float nvs[8] = {nva.x, nva.y, nva.z, nva.w, nvb.x, nvb.y, nvb.z, nvb.w};
    float evs[8] = {eva.x, eva.y, eva.z, eva.w, evb.x, evb.y, evb.z, evb.w};

    // independent row gathers, all issued before first MFMA
    bf16x8 nfr[8];
#pragma unroll
    for (int kb = 0; kb < 8; ++kb)
        nfr[kb] = *(const bf16x8*)(nfeat_bf + ncs[kb] * DD + half * 8);

    f32x4 acc = {0.f, 0.f, 0.f, 0.f};
#pragma unroll
    for (int kb = 0; kb < 8; ++kb) {
        unsigned int b = (be16 >> (2 * kb)) & 3u;
        bf16x8 blo = (b & 1) ? bq1 : bq0;
        bf16x8 bhi = (b & 1) ? bq3 : bq2;
        bf16x8 bsel = (b & 2) ? bhi : blo;
        float nv = nvs[kb], ev = evs[kb];
        bf16x8 af;
#pragma unroll
        for (int j = 0; j < 8; ++j)
            af[j] = (__bf16)fmaf(nv, (float)nfr[kb][j], ev * (float)bsel[j]);
        acc = __builtin_amdgcn_mfma_f32_16x16x32_bf16(af, wf[kb], acc, 0, 0, 0);
    }

    // epilogue: lane commits channel `col` of its quad's 4 perms
    int   prs[4] = {pr.x, pr.y, pr.z, pr.w};
    float pvs[4] = {pvv.x, pvv.y, pvv.z, pvv.w};
#pragma unroll
    for (int r = 0; r < 4; ++r) {
        float v = fmaxf(acc[r] + bias_c, 0.f) * pvs[r];
        unsafeAtomicAdd(out + (size_t)prs[r] * DD + col, v);
    }
}

__global__ __launch_bounds__(256) void gate_kernel(
    const float* __restrict__ degs,  // [N]
    const float* __restrict__ W0,    // [1,32]
    const float* __restrict__ b0,    // [32]
    const float* __restrict__ W1,    // [32,16]
    const float* __restrict__ b1,    // [16]
    float* __restrict__ out)         // [N,16] in-place multiply
{
    int n = blockIdx.x * 256 + threadIdx.x;
    if (n >= NN) return;
    float dg = degs[n];
    float4 a0 = ((const float4*)b1)[0];
    float4 a1 = ((const float4*)b1)[1];
    float4 a2 = ((const float4*)b1)[2];
    float4 a3 = ((const float4*)b1)[3];
#pragma unroll
    for (int j = 0; j < 32; ++j) {
        float h = fmaxf(fmaf(dg, W0[j], b0[j]), 0.f);
        const float4* w1r = (const float4*)(W1 + j * 16);
        a0 = fma4(h, w1r[0], a0);
        a1 = fma4(h, w1r[1], a1);
        a2 = fma4(h, w1r[2], a2);
        a3 = fma4(h, w1r[3], a3);
    }
    float4* o = (float4*)(out + (size_t)n * DD);
    float4 v0 = o[0], v1 = o[1], v2 = o[2], v3 = o[3];
    v0.x *= a0.x; v0.y *= a0.y; v0.z *= a0.z; v0.w *= a0.w;
    v1.x *= a1.x; v1.y *= a1.y; v1.z *= a1.z; v1.w *= a1.w;
    v2.x *= a2.x; v2.y *= a2.y; v2.z *= a2.z; v2.w *= a2.w;
    v3.x *= a3.x; v3.y *= a3.y; v3.z *= a3.z; v3.w *= a3.w;
    o[0] = v0; o[1] = v1; o[2] = v2; o[3] = v3;
}

extern "C" void kernel_launch(void* const* d_in, const int* in_sizes, int n_in,
                              void* d_out, int out_size, void* d_ws, size_t ws_size,
                              hipStream_t stream) {
    const float* nfeat     = (const float*)d_in[0];
    const int*   efeat_idx = (const int*)d_in[1];
    // d_in[2] n_row = arange(M), unused
    const int*   n_col     = (const int*)d_in[3];
    const float* n_val     = (const float*)d_in[4];
    // d_in[5] e_row = arange(M), unused
    const int*   e_col     = (const int*)d_in[6];
    const float* e_val     = (const float*)d_in[7];
    const int*   p_row     = (const int*)d_in[8];
    // d_in[9] p_col = arange(P), unused
    const float* p_val     = (const float*)d_in[10];
    const float* degs      = (const float*)d_in[11];
    const float* weights   = (const float*)d_in[12];
    const float* bias      = (const float*)d_in[13];
    const float* W0        = (const float*)d_in[14];
    const float* b0        = (const float*)d_in[15];
    const float* W1        = (const float*)d_in[16];
    const float* b1        = (const float*)d_in[17];
    const float* bond_emb  = (const float*)d_in[18];

    float* out = (float*)d_out;

    // ws layout (16B-aligned blocks): wfrag 8KB | nfeat_bf 3.2MB | bond 128B | be2 1MB
    // Total 4,208,320 B — proven-safe footprint (R5-R7); do not grow.
    char* wsb = (char*)d_ws;
    __bf16*        wfrag    = (__bf16*)wsb;                                // 8192 B
    __bf16*        nfeat_bf = (__bf16*)(wsb + 8192);                       // 3,200,000 B
    __bf16*        bond_bf  = (__bf16*)(wsb + 8192 + 3200000);             // 128 B
    unsigned char* be2      = (unsigned char*)(wsb + 8192 + 3200000 + 128);// 1,000,000 B

    // grid must cover max(NN*DD, MM/4) = 1.6M threads
    init_kernel<<<(NN * DD + 255) / 256, 256, 0, stream>>>(
        weights, nfeat, bond_emb, e_col, efeat_idx,
        wfrag, nfeat_bf, bond_bf, be2, out);

    // one 1-wave block per 16-perm tile: fine-grained scheduling
    perm_kernel<<<NTILES, 64, 0, stream>>>(
        nfeat_bf, n_col, n_val, e_val, be2, p_row, p_val,
        wfrag, bias, bond_bf, out);

    gate_kernel<<<(NN + 255) / 256, 256, 0, stream>>>(degs, W0, b0, W1, b1, out);
}